// Round 11
// baseline (246.360 us; speedup 1.0000x reference)
//
#include <hip/hip_runtime.h>
#include <stdint.h>

// CrossAttention as 4 GEMMs (KV, Q, S, PV) + fused softmax epilogues.
// out = softmax((hs@Wq)(dhs@Wk)^T / 32) @ (dhs@Wv);  B=4, QL=KL=2048, D=1024.
// R11: revert R10 merge (tail quantization: 384 blocks = 1.5 rounds); back to
// R7 (best, 160.06us): every GEMM launch exactly 256 blocks. One change vs R7:
// K-tile loop manually unrolled by 2 with compile-time buffer parity (NT is
// always even) -- folds (t&1) addressing off the critical path. Ledger
// (barriers / vmcnt values / stage slots / R3 tail rule) unchanged.

typedef __bf16 bf16_t;
typedef __bf16 bf16x8 __attribute__((ext_vector_type(8)));
typedef __bf16 bf16x4 __attribute__((ext_vector_type(4)));
typedef float  f32x4  __attribute__((ext_vector_type(4)));

#define MFMA_BF16(A, B, C) __builtin_amdgcn_mfma_f32_16x16x32_bf16((A), (B), (C), 0, 0, 0)
#define ATTN_SHIFT 16.0f

__device__ __forceinline__ void async_copy16(const void* g, void* l) {
  __builtin_amdgcn_global_load_lds(
      (const __attribute__((address_space(1))) uint32_t*)g,
      (__attribute__((address_space(3))) uint32_t*)l, 16, 0, 0);
}

// ---------------- fused prep: cast hs/dhs -> bf16, zero rowsum, transpose weights ----------------
__global__ void prep_kernel(const float* __restrict__ a, const float* __restrict__ b,
                            bf16_t* __restrict__ ab, bf16_t* __restrict__ bb,
                            float* __restrict__ rowsum,
                            const float* __restrict__ Wq, const float* __restrict__ Wkv,
                            bf16_t* __restrict__ WqT, bf16_t* __restrict__ WkvT) {
  __shared__ float tile[32][33];
  const int bx = blockIdx.x, tid = threadIdx.x;
  if (bx < 2048) {
    int gtid = bx * 256 + tid;
    if (gtid < 8192) rowsum[gtid] = 0.f;
    const int n = 8 * 1024 * 1024, stride = 2048 * 256 * 4;
    for (int i = gtid * 4; i < n; i += stride) {
      float4 v = *(const float4*)(a + i);
      float4 w = *(const float4*)(b + i);
      bf16x4 o, p;
      o[0] = (bf16_t)v.x; o[1] = (bf16_t)v.y; o[2] = (bf16_t)v.z; o[3] = (bf16_t)v.w;
      p[0] = (bf16_t)w.x; p[1] = (bf16_t)w.y; p[2] = (bf16_t)w.z; p[3] = (bf16_t)w.w;
      *(bf16x4*)(ab + i) = o;
      *(bf16x4*)(bb + i) = p;
    }
  } else {
    // transpose+cast: 3072 blocks = 32 r-blocks x 96 col-blocks
    int t = bx - 2048;
    int r0 = (t / 96) * 32, cb = t % 96;
    const float* src; bf16_t* dst; int R, C; float scale;
    if (cb < 32) { src = Wq;  dst = WqT;  R = 1024; C = 1024; scale = 0.03125f; }
    else         { src = Wkv; dst = WkvT; R = 1024; C = 2048; scale = 1.0f; cb -= 32; }
    int c0 = cb * 32;
    int tx = tid & 31, ty = tid >> 5;  // 32 x 8
#pragma unroll
    for (int i = 0; i < 4; ++i) {
      int r = ty + i * 8;
      tile[r][tx] = src[(size_t)(r0 + r) * C + c0 + tx] * scale;
    }
    __syncthreads();
#pragma unroll
    for (int i = 0; i < 4; ++i) {
      int c = ty + i * 8;
      dst[(size_t)(c0 + c) * R + r0 + tx] = (bf16_t)tile[tx][c];
    }
  }
}

// ---------------- K-half pipelined GEMM: C[M,N] = A[M,K] @ Bt[N,K]^T ----------------
// BM=256, BK=64, 8 waves. BN=256: 2x4 wave grid (wave tile 128x64);
// BN=128: 4x2 wave grid (wave tile 64x64).
// Per tile t (buf p=t&1, compile-time via unroll-by-2):
//   [read kh1 frags from buf p]  MFMA(kh0)          <- LDS serve under MFMA
//   lgkm0; bar  (buf p read-dead)
//   stage(t+2)->buf p; vmcnt(SOPS | 0 at tail); bar (buf p^1 ready)
//   [read kh0 frags of t+1 from buf p^1]  MFMA(kh1)
// EPI 0: bf16 store. 1: P=exp(acc-16)+rowsum. 2: fp32/rowsum. 4: K + V->VT.
template <int BN, int EPI>
__global__ __launch_bounds__(512, 2) void gemm8(
    const bf16_t* __restrict__ A, int lda, size_t sA,
    const bf16_t* __restrict__ Bt, int ldb, size_t sB,
    void* __restrict__ Cv, int ldc, size_t sC,
    void* __restrict__ Cv2, int nb, int bpb, int K, float* __restrict__ rowsum) {
  constexpr int ABYTES = 256 * 64 * 2;   // 32 KiB per A buffer
  constexpr int BBYTES = BN * 64 * 2;    // 32/16 KiB per B buffer
  constexpr int WC   = (BN == 256) ? 4 : 2;
  constexpr int MW   = (BN == 256) ? 128 : 64;  // wave-tile rows
  constexpr int NW   = BN / WC;                 // wave-tile cols (64)
  constexpr int NRF  = MW / 16;                 // 8 or 4
  constexpr int NCF2 = NW / 16;                 // 4
  __shared__ char smem[2 * ABYTES + 2 * BBYTES];

  // T1 XCD-chunk swizzle (grid always a multiple of 8 here)
  const int bx0 = blockIdx.x;
  const int q8 = gridDim.x >> 3;
  const int swz = (bx0 & 7) * q8 + (bx0 >> 3);
  const int bz = swz / bpb;
  const int rr = swz % bpb;
  const int m0 = (rr / nb) << 8;
  const int n0 = (rr % nb) * BN;

  const bf16_t* Ab = A + (size_t)bz * sA;
  const bf16_t* Bb = Bt + (size_t)bz * sB;
  const int tid = threadIdx.x, w = tid >> 6, l = tid & 63;
  const int l15 = l & 15, l4 = l >> 4;
  const int wc = w & (WC - 1), wr = w / WC;
  const int NT = K >> 6;                 // always even here (16 or 32)

  // staging: lane covers row (8w + l>>3), pre-swizzled granule (T2 rule #21)
  const int lrow = l >> 3;
  const int gcol = ((l & 7) ^ lrow) << 3;
  const bf16_t* PA = Ab + (size_t)(m0 + 8 * w + lrow) * lda + gcol;
  const bf16_t* PB = Bb + (size_t)(n0 + 8 * w + lrow) * ldb + gcol;

  const int sw16 = (l15 & 7) << 4;       // read-side swizzle XOR (bytes)
  const int aoff0 = (wr * MW + l15) * 128;
  const int boff0 = (wc * NW + l15) * 128;

  f32x4 acc[NRF][NCF2] = {};
  bf16x8 afA[NRF], bfA[NCF2], afB[NRF], bfB[NCF2];

  auto stageA = [&](int t, int h, int par) {  // h: 0 = rows 0-127, 1 = rows 128-255
    const bf16_t* s = PA + (size_t)(h * 128) * lda + (t << 6);
    char* d = smem + par * ABYTES + h * 16384 + w * 1024;
    async_copy16(s, d);
    async_copy16(s + (size_t)64 * lda, d + 8192);
  };
  auto stageB = [&](int t, int h, int par) {
    const bf16_t* s = PB + (size_t)(h * (BN / 2)) * ldb + (t << 6);
    char* d = smem + 2 * ABYTES + par * BBYTES + h * (BBYTES / 2) + w * 1024;
    async_copy16(s, d);
    if constexpr (BN == 256) async_copy16(s + (size_t)64 * ldb, d + 8192);
  };
  auto stageT = [&](int t, int par) {
    if (t >= NT) return;
    stageA(t, 0, par); stageA(t, 1, par); stageB(t, 0, par); stageB(t, 1, par);
  };
  auto rdA = [&](bf16x8* dst, const char* base, int kh) {
#pragma unroll
    for (int rf = 0; rf < NRF; ++rf)
      dst[rf] = *(const bf16x8*)(base + aoff0 + rf * 2048 + (((kh * 4 + l4) << 4) ^ sw16));
  };
  auto rdB = [&](bf16x8* dst, const char* base, int kh) {
#pragma unroll
    for (int cf = 0; cf < NCF2; ++cf)
      dst[cf] = *(const bf16x8*)(base + boff0 + cf * 2048 + (((kh * 4 + l4) << 4) ^ sw16));
  };
  auto mfma_half = [&](const bf16x8* afx, const bf16x8* bfx) {
#pragma unroll
    for (int rf = 0; rf < NRF; ++rf)
#pragma unroll
      for (int cf = 0; cf < NCF2; ++cf)
        acc[rf][cf] = MFMA_BF16(afx[rf], bfx[cf], acc[rf][cf]);
  };

  // ---- prologue: stage tiles 0 and 1; wait tile0; preload kh0 frags ----
  stageT(0, 0);
  __builtin_amdgcn_sched_barrier(0);
  stageT(1, 1);
  __builtin_amdgcn_sched_barrier(0);
  if constexpr (BN == 256) asm volatile("s_waitcnt vmcnt(8)" ::: "memory");
  else                     asm volatile("s_waitcnt vmcnt(6)" ::: "memory");
  __builtin_amdgcn_s_barrier();
  __builtin_amdgcn_sched_barrier(0);
  rdA(afA, smem, 0);
  rdB(bfA, smem + 2 * ABYTES, 0);

  // body for tile t with compile-time buffer parity: cur = par, next = par^1
  auto body = [&](int t, int par) {
    const char* Ac = smem + par * ABYTES;
    const char* Bc = smem + 2 * ABYTES + par * BBYTES;
    const char* An = smem + (par ^ 1) * ABYTES;
    const char* Bn = smem + 2 * ABYTES + (par ^ 1) * BBYTES;
    // ---- half 0: issue kh1 reads (buf p), MFMA kh0 under them ----
    rdA(afB, Ac, 1);
    rdB(bfB, Bc, 1);
    __builtin_amdgcn_sched_barrier(0);
    __builtin_amdgcn_s_setprio(1);
    mfma_half(afA, bfA);
    __builtin_amdgcn_s_setprio(0);
    __builtin_amdgcn_sched_barrier(0);
    asm volatile("s_waitcnt lgkmcnt(0)" ::: "memory");  // buf p read-dead (this wave)
    __builtin_amdgcn_s_barrier();                       // ... for all waves
    __builtin_amdgcn_sched_barrier(0);
    // ---- stage t+2 into buf p; ensure buf p^1 (tile t+1) resident ----
    stageT(t + 2, par);
    __builtin_amdgcn_sched_barrier(0);
    if (t < NT - 2) {
      if constexpr (BN == 256) asm volatile("s_waitcnt vmcnt(8)" ::: "memory");
      else                     asm volatile("s_waitcnt vmcnt(6)" ::: "memory");
    } else {
      // tail: t+2 skipped -> newest in-flight are t+1's own stages (R3 rule)
      asm volatile("s_waitcnt vmcnt(0)" ::: "memory");
    }
    __builtin_amdgcn_s_barrier();
    __builtin_amdgcn_sched_barrier(0);
    // ---- half 1: issue kh0 reads of t+1 (buf p^1), MFMA kh1 under them ----
    if (t + 1 < NT) {
      rdA(afA, An, 0);
      rdB(bfA, Bn, 0);
    }
    __builtin_amdgcn_sched_barrier(0);
    __builtin_amdgcn_s_setprio(1);
    mfma_half(afB, bfB);
    __builtin_amdgcn_s_setprio(0);
    __builtin_amdgcn_sched_barrier(0);
  };

#pragma unroll 1
  for (int t = 0; t < NT; t += 2) {
    body(t, 0);
    body(t + 1, 1);
  }

  __syncthreads();  // before LDS reuse in epilogue

  if constexpr (EPI == 0) {
    bf16_t* Cb = (bf16_t*)Cv + (size_t)bz * sC;
#pragma unroll
    for (int rf = 0; rf < NRF; ++rf)
#pragma unroll
      for (int cf = 0; cf < NCF2; ++cf) {
        int grow = m0 + wr * MW + rf * 16 + l4 * 4;
        int gc = n0 + wc * NW + cf * 16 + l15;
#pragma unroll
        for (int r = 0; r < 4; ++r)
          Cb[(size_t)(grow + r) * ldc + gc] = (bf16_t)acc[rf][cf][r];
      }
  } else if constexpr (EPI == 1) {
    bf16_t* Cb = (bf16_t*)Cv + (size_t)bz * sC;
    float* rsh = (float*)smem;
    if (tid < 256) rsh[tid] = 0.f;
    __syncthreads();
#pragma unroll
    for (int rf = 0; rf < NRF; ++rf)
#pragma unroll
      for (int r = 0; r < 4; ++r) {
        int lr = wr * MW + rf * 16 + l4 * 4 + r;
        float s = 0.f;
#pragma unroll
        for (int cf = 0; cf < NCF2; ++cf) {
          float p = __expf(acc[rf][cf][r] - ATTN_SHIFT);
          bf16_t pb = (bf16_t)p;
          Cb[(size_t)(m0 + lr) * ldc + n0 + wc * NW + cf * 16 + l15] = pb;
          s += (float)pb;  // sum the ROUNDED numerator
        }
        s += __shfl_xor(s, 1); s += __shfl_xor(s, 2);
        s += __shfl_xor(s, 4); s += __shfl_xor(s, 8);
        if (l15 == 0) atomicAdd(&rsh[lr], s);
      }
    __syncthreads();
    if (tid < 256) atomicAdd(&rowsum[(size_t)bz * 2048 + m0 + tid], rsh[tid]);
  } else if constexpr (EPI == 2) {
    float* rsh = (float*)smem;
    if (tid < 256) rsh[tid] = rowsum[(size_t)bz * 2048 + m0 + tid];
    __syncthreads();
    float* Cb = (float*)Cv + (size_t)bz * sC;
#pragma unroll
    for (int rf = 0; rf < NRF; ++rf)
#pragma unroll
      for (int r = 0; r < 4; ++r) {
        float inv = 1.0f / rsh[wr * MW + rf * 16 + l4 * 4 + r];
        int grow = m0 + wr * MW + rf * 16 + l4 * 4 + r;
#pragma unroll
        for (int cf = 0; cf < NCF2; ++cf)
          Cb[(size_t)grow * ldc + n0 + wc * NW + cf * 16 + l15] = acc[rf][cf][r] * inv;
      }
  } else {  // EPI == 4: fused K/V projection epilogue
    if (n0 < 1024) {
      bf16_t* Cb = (bf16_t*)Cv;  // K output, ldc = 1024, rows = 8192 (batch-folded)
#pragma unroll
      for (int rf = 0; rf < NRF; ++rf)
#pragma unroll
        for (int cf = 0; cf < NCF2; ++cf) {
          int grow = m0 + wr * MW + rf * 16 + l4 * 4;
          int gc = n0 + wc * NW + cf * 16 + l15;
#pragma unroll
          for (int r = 0; r < 4; ++r)
            Cb[(size_t)(grow + r) * ldc + gc] = (bf16_t)acc[rf][cf][r];
        }
    } else {
      bf16_t* VTb = (bf16_t*)Cv2;  // VT[b][d][kl]
#pragma unroll
      for (int rf = 0; rf < NRF; ++rf)
#pragma unroll
        for (int cf = 0; cf < NCF2; ++cf) {
          int grow0 = m0 + wr * MW + rf * 16 + l4 * 4;
          int b = grow0 >> 11, kl = grow0 & 2047;
          int d = (n0 - 1024) + wc * NW + cf * 16 + l15;
          bf16x4 v;
#pragma unroll
          for (int r = 0; r < 4; ++r) v[r] = (bf16_t)acc[rf][cf][r];
          *(bf16x4*)(VTb + (size_t)b * (1024 * 2048) + (size_t)d * 2048 + kl) = v;
        }
    }
  }
}

// ---------------- launcher ----------------
extern "C" void kernel_launch(void* const* d_in, const int* in_sizes, int n_in,
                              void* d_out, int out_size, void* d_ws, size_t ws_size,
                              hipStream_t stream) {
  const float* hs  = (const float*)d_in[0];   // [4,2048,1024]
  const float* dhs = (const float*)d_in[1];   // [4,2048,1024]
  const float* Wq  = (const float*)d_in[2];   // [1024,1024]
  const float* Wkv = (const float*)d_in[3];   // [1024,2048]
  float* out = (float*)d_out;

  const size_t M1 = 1024 * 1024;
  bf16_t* WqT  = (bf16_t*)d_ws;          // 1M elems  (Wq^T * 1/32)
  bf16_t* WkvT = WqT + M1;               // 2M elems  (rows 0..1023 = Wk^T, 1024..2047 = Wv^T)
  bf16_t* AB   = WkvT + 2 * M1;          // 16M elems shared region:
  bf16_t* dhsb = AB;                     //   dhs bf16 (dead after KV gemm)
  bf16_t* hsb  = AB + 8 * M1;            //   hs bf16  (dead after Q gemm)
  bf16_t* P    = AB;                     //   then: P [4][2048][2048]
  bf16_t* Kb   = AB + 16 * M1;           // 8M elems  K [4*2048][1024]
  bf16_t* VTb  = Kb + 8 * M1;            // 8M elems  VT [4][1024][2048]
  bf16_t* Qb   = VTb + 8 * M1;           // 8M elems  Q [4*2048][1024] (pre-scaled 1/32)
  float* rowsum = (float*)(Qb + 8 * M1); // 8192 fp32

  prep_kernel<<<2048 + 3072, 256, 0, stream>>>(dhs, hs, dhsb, hsb, rowsum,
                                               Wq, Wkv, WqT, WkvT);

  // KV = dhs @ Wkv : M=8192, N=2048, K=1024; K-half -> Kb, V-half -> VT
  gemm8<256, 4><<<256, 512, 0, stream>>>(
      dhsb, 1024, 0, WkvT, 1024, 0, Kb, 1024, 0, VTb, 8, 256, 1024, nullptr);
  // Q = hs @ (Wq/32) : M=8192, N=1024, K=1024
  gemm8<128, 0><<<256, 512, 0, stream>>>(
      hsb, 1024, 0, WqT, 1024, 0, Qb, 1024, 0, nullptr, 8, 256, 1024, nullptr);
  // P = exp(Q K^T - 16) + rowsums : per batch M=N=2048, K=1024
  gemm8<256, 1><<<256, 512, 0, stream>>>(
      Qb, 1024, (size_t)2048 * 1024, Kb, 1024, (size_t)2048 * 1024,
      P, 2048, (size_t)2048 * 2048, nullptr, 8, 64, 1024, rowsum);
  // out = (P @ V) / rowsum : per batch M=2048, N=1024, K=2048
  gemm8<128, 2><<<256, 512, 0, stream>>>(
      P, 2048, (size_t)2048 * 2048, VTb, 2048, (size_t)1024 * 2048,
      out, 1024, (size_t)2048 * 1024, nullptr, 8, 64, 2048, rowsum);
}

// Round 12
// 160.051 us; speedup vs baseline: 1.5393x; 1.5393x over previous
//
#include <hip/hip_runtime.h>
#include <stdint.h>

// CrossAttention as 4 GEMMs (KV, Q, S, PV) + fused softmax epilogues.
// out = softmax((hs@Wq)(dhs@Wk)^T / 32) @ (dhs@Wv);  B=4, QL=KL=2048, D=1024.
// R12: exact revert to R7 (best measured: 160.06us). R11's unroll-by-2
// spilled to scratch (WRITE_SIZE 33->156MB, MfmaUtil 27->14%); reverted.
// Structure: K-half software-pipelined fragments -- ds_read of the NEXT half
// issues under the CURRENT half's MFMA cluster. 2 barriers/K-tile.
// T1 XCD swizzle + T2 both-sides swizzle + T4 counted vmcnt (R3 tail rule)
// + T5 setprio. All GEMM launches exactly 256 blocks (1/CU).

typedef __bf16 bf16_t;
typedef __bf16 bf16x8 __attribute__((ext_vector_type(8)));
typedef __bf16 bf16x4 __attribute__((ext_vector_type(4)));
typedef float  f32x4  __attribute__((ext_vector_type(4)));

#define MFMA_BF16(A, B, C) __builtin_amdgcn_mfma_f32_16x16x32_bf16((A), (B), (C), 0, 0, 0)
#define ATTN_SHIFT 16.0f

__device__ __forceinline__ void async_copy16(const void* g, void* l) {
  __builtin_amdgcn_global_load_lds(
      (const __attribute__((address_space(1))) uint32_t*)g,
      (__attribute__((address_space(3))) uint32_t*)l, 16, 0, 0);
}

// ---------------- fused prep: cast hs/dhs -> bf16, zero rowsum, transpose weights ----------------
__global__ void prep_kernel(const float* __restrict__ a, const float* __restrict__ b,
                            bf16_t* __restrict__ ab, bf16_t* __restrict__ bb,
                            float* __restrict__ rowsum,
                            const float* __restrict__ Wq, const float* __restrict__ Wkv,
                            bf16_t* __restrict__ WqT, bf16_t* __restrict__ WkvT) {
  __shared__ float tile[32][33];
  const int bx = blockIdx.x, tid = threadIdx.x;
  if (bx < 2048) {
    int gtid = bx * 256 + tid;
    if (gtid < 8192) rowsum[gtid] = 0.f;
    const int n = 8 * 1024 * 1024, stride = 2048 * 256 * 4;
    for (int i = gtid * 4; i < n; i += stride) {
      float4 v = *(const float4*)(a + i);
      float4 w = *(const float4*)(b + i);
      bf16x4 o, p;
      o[0] = (bf16_t)v.x; o[1] = (bf16_t)v.y; o[2] = (bf16_t)v.z; o[3] = (bf16_t)v.w;
      p[0] = (bf16_t)w.x; p[1] = (bf16_t)w.y; p[2] = (bf16_t)w.z; p[3] = (bf16_t)w.w;
      *(bf16x4*)(ab + i) = o;
      *(bf16x4*)(bb + i) = p;
    }
  } else {
    // transpose+cast: 3072 blocks = 32 r-blocks x 96 col-blocks
    int t = bx - 2048;
    int r0 = (t / 96) * 32, cb = t % 96;
    const float* src; bf16_t* dst; int R, C; float scale;
    if (cb < 32) { src = Wq;  dst = WqT;  R = 1024; C = 1024; scale = 0.03125f; }
    else         { src = Wkv; dst = WkvT; R = 1024; C = 2048; scale = 1.0f; cb -= 32; }
    int c0 = cb * 32;
    int tx = tid & 31, ty = tid >> 5;  // 32 x 8
#pragma unroll
    for (int i = 0; i < 4; ++i) {
      int r = ty + i * 8;
      tile[r][tx] = src[(size_t)(r0 + r) * C + c0 + tx] * scale;
    }
    __syncthreads();
#pragma unroll
    for (int i = 0; i < 4; ++i) {
      int c = ty + i * 8;
      dst[(size_t)(c0 + c) * R + r0 + tx] = (bf16_t)tile[tx][c];
    }
  }
}

// ---------------- K-half pipelined GEMM: C[M,N] = A[M,K] @ Bt[N,K]^T ----------------
// BM=256, BK=64, 8 waves. BN=256: 2x4 wave grid (wave tile 128x64);
// BN=128: 4x2 wave grid (wave tile 64x64).
// Per tile t (buf p=t&1):
//   [read kh1 frags from buf p]  MFMA(kh0)          <- LDS serve under MFMA
//   lgkm0; bar  (buf p read-dead)
//   stage(t+2)->buf p; vmcnt(SOPS | 0 at tail); bar (buf p^1 ready)
//   [read kh0 frags of t+1 from buf p^1]  MFMA(kh1)
// EPI 0: bf16 store. 1: P=exp(acc-16)+rowsum. 2: fp32/rowsum. 4: K + V->VT.
template <int BN, int EPI>
__global__ __launch_bounds__(512, 2) void gemm8(
    const bf16_t* __restrict__ A, int lda, size_t sA,
    const bf16_t* __restrict__ Bt, int ldb, size_t sB,
    void* __restrict__ Cv, int ldc, size_t sC,
    void* __restrict__ Cv2, int nb, int bpb, int K, float* __restrict__ rowsum) {
  constexpr int ABYTES = 256 * 64 * 2;   // 32 KiB per A buffer
  constexpr int BBYTES = BN * 64 * 2;    // 32/16 KiB per B buffer
  constexpr int WC   = (BN == 256) ? 4 : 2;
  constexpr int MW   = (BN == 256) ? 128 : 64;  // wave-tile rows
  constexpr int NW   = BN / WC;                 // wave-tile cols (64)
  constexpr int NRF  = MW / 16;                 // 8 or 4
  constexpr int NCF2 = NW / 16;                 // 4
  __shared__ char smem[2 * ABYTES + 2 * BBYTES];

  // T1 XCD-chunk swizzle (grid always a multiple of 8 here)
  const int bx0 = blockIdx.x;
  const int q8 = gridDim.x >> 3;
  const int swz = (bx0 & 7) * q8 + (bx0 >> 3);
  const int bz = swz / bpb;
  const int rr = swz % bpb;
  const int m0 = (rr / nb) << 8;
  const int n0 = (rr % nb) * BN;

  const bf16_t* Ab = A + (size_t)bz * sA;
  const bf16_t* Bb = Bt + (size_t)bz * sB;
  const int tid = threadIdx.x, w = tid >> 6, l = tid & 63;
  const int l15 = l & 15, l4 = l >> 4;
  const int wc = w & (WC - 1), wr = w / WC;
  const int NT = K >> 6;

  // staging: lane covers row (8w + l>>3), pre-swizzled granule (T2 rule #21)
  const int lrow = l >> 3;
  const int gcol = ((l & 7) ^ lrow) << 3;
  const bf16_t* PA = Ab + (size_t)(m0 + 8 * w + lrow) * lda + gcol;
  const bf16_t* PB = Bb + (size_t)(n0 + 8 * w + lrow) * ldb + gcol;

  const int sw16 = (l15 & 7) << 4;       // read-side swizzle XOR (bytes)
  const int aoff0 = (wr * MW + l15) * 128;
  const int boff0 = (wc * NW + l15) * 128;

  f32x4 acc[NRF][NCF2] = {};
  bf16x8 afA[NRF], bfA[NCF2], afB[NRF], bfB[NCF2];

  auto stageA = [&](int t, int h) {      // h: 0 = rows 0-127, 1 = rows 128-255
    const bf16_t* s = PA + (size_t)(h * 128) * lda + (t << 6);
    char* d = smem + (t & 1) * ABYTES + h * 16384 + w * 1024;
    async_copy16(s, d);
    async_copy16(s + (size_t)64 * lda, d + 8192);
  };
  auto stageB = [&](int t, int h) {
    const bf16_t* s = PB + (size_t)(h * (BN / 2)) * ldb + (t << 6);
    char* d = smem + 2 * ABYTES + (t & 1) * BBYTES + h * (BBYTES / 2) + w * 1024;
    async_copy16(s, d);
    if constexpr (BN == 256) async_copy16(s + (size_t)64 * ldb, d + 8192);
  };
  auto stageT = [&](int t) {
    if (t >= NT) return;
    stageA(t, 0); stageA(t, 1); stageB(t, 0); stageB(t, 1);
  };
  auto rdA = [&](bf16x8* dst, const char* base, int kh) {
#pragma unroll
    for (int rf = 0; rf < NRF; ++rf)
      dst[rf] = *(const bf16x8*)(base + aoff0 + rf * 2048 + (((kh * 4 + l4) << 4) ^ sw16));
  };
  auto rdB = [&](bf16x8* dst, const char* base, int kh) {
#pragma unroll
    for (int cf = 0; cf < NCF2; ++cf)
      dst[cf] = *(const bf16x8*)(base + boff0 + cf * 2048 + (((kh * 4 + l4) << 4) ^ sw16));
  };
  auto mfma_half = [&](const bf16x8* afx, const bf16x8* bfx) {
#pragma unroll
    for (int rf = 0; rf < NRF; ++rf)
#pragma unroll
      for (int cf = 0; cf < NCF2; ++cf)
        acc[rf][cf] = MFMA_BF16(afx[rf], bfx[cf], acc[rf][cf]);
  };

  // ---- prologue: stage tiles 0 and 1; wait tile0; preload kh0 frags ----
  stageT(0);
  __builtin_amdgcn_sched_barrier(0);
  stageT(1);
  __builtin_amdgcn_sched_barrier(0);
  if constexpr (BN == 256) asm volatile("s_waitcnt vmcnt(8)" ::: "memory");
  else                     asm volatile("s_waitcnt vmcnt(6)" ::: "memory");
  __builtin_amdgcn_s_barrier();
  __builtin_amdgcn_sched_barrier(0);
  rdA(afA, smem, 0);
  rdB(bfA, smem + 2 * ABYTES, 0);

  for (int t = 0; t < NT; ++t) {
    const char* Ac = smem + (t & 1) * ABYTES;
    const char* Bc = smem + 2 * ABYTES + (t & 1) * BBYTES;
    const char* An = smem + ((t + 1) & 1) * ABYTES;
    const char* Bn = smem + 2 * ABYTES + ((t + 1) & 1) * BBYTES;
    // ---- half 0: issue kh1 reads (buf p), MFMA kh0 under them ----
    rdA(afB, Ac, 1);
    rdB(bfB, Bc, 1);
    __builtin_amdgcn_sched_barrier(0);
    __builtin_amdgcn_s_setprio(1);
    mfma_half(afA, bfA);
    __builtin_amdgcn_s_setprio(0);
    __builtin_amdgcn_sched_barrier(0);
    asm volatile("s_waitcnt lgkmcnt(0)" ::: "memory");  // buf p read-dead (this wave)
    __builtin_amdgcn_s_barrier();                       // ... for all waves
    __builtin_amdgcn_sched_barrier(0);
    // ---- stage t+2 into buf p; ensure buf p^1 (tile t+1) resident ----
    stageT(t + 2);
    __builtin_amdgcn_sched_barrier(0);
    if (t < NT - 2) {
      if constexpr (BN == 256) asm volatile("s_waitcnt vmcnt(8)" ::: "memory");
      else                     asm volatile("s_waitcnt vmcnt(6)" ::: "memory");
    } else {
      // tail: t+2 skipped -> newest in-flight are t+1's own stages (R3 rule)
      asm volatile("s_waitcnt vmcnt(0)" ::: "memory");
    }
    __builtin_amdgcn_s_barrier();
    __builtin_amdgcn_sched_barrier(0);
    // ---- half 1: issue kh0 reads of t+1 (buf p^1), MFMA kh1 under them ----
    if (t + 1 < NT) {
      rdA(afA, An, 0);
      rdB(bfA, Bn, 0);
    }
    __builtin_amdgcn_sched_barrier(0);
    __builtin_amdgcn_s_setprio(1);
    mfma_half(afB, bfB);
    __builtin_amdgcn_s_setprio(0);
    __builtin_amdgcn_sched_barrier(0);
  }

  __syncthreads();  // before LDS reuse in epilogue

  if constexpr (EPI == 0) {
    bf16_t* Cb = (bf16_t*)Cv + (size_t)bz * sC;
#pragma unroll
    for (int rf = 0; rf < NRF; ++rf)
#pragma unroll
      for (int cf = 0; cf < NCF2; ++cf) {
        int grow = m0 + wr * MW + rf * 16 + l4 * 4;
        int gc = n0 + wc * NW + cf * 16 + l15;
#pragma unroll
        for (int r = 0; r < 4; ++r)
          Cb[(size_t)(grow + r) * ldc + gc] = (bf16_t)acc[rf][cf][r];
      }
  } else if constexpr (EPI == 1) {
    bf16_t* Cb = (bf16_t*)Cv + (size_t)bz * sC;
    float* rsh = (float*)smem;
    if (tid < 256) rsh[tid] = 0.f;
    __syncthreads();
#pragma unroll
    for (int rf = 0; rf < NRF; ++rf)
#pragma unroll
      for (int r = 0; r < 4; ++r) {
        int lr = wr * MW + rf * 16 + l4 * 4 + r;
        float s = 0.f;
#pragma unroll
        for (int cf = 0; cf < NCF2; ++cf) {
          float p = __expf(acc[rf][cf][r] - ATTN_SHIFT);
          bf16_t pb = (bf16_t)p;
          Cb[(size_t)(m0 + lr) * ldc + n0 + wc * NW + cf * 16 + l15] = pb;
          s += (float)pb;  // sum the ROUNDED numerator
        }
        s += __shfl_xor(s, 1); s += __shfl_xor(s, 2);
        s += __shfl_xor(s, 4); s += __shfl_xor(s, 8);
        if (l15 == 0) atomicAdd(&rsh[lr], s);
      }
    __syncthreads();
    if (tid < 256) atomicAdd(&rowsum[(size_t)bz * 2048 + m0 + tid], rsh[tid]);
  } else if constexpr (EPI == 2) {
    float* rsh = (float*)smem;
    if (tid < 256) rsh[tid] = rowsum[(size_t)bz * 2048 + m0 + tid];
    __syncthreads();
    float* Cb = (float*)Cv + (size_t)bz * sC;
#pragma unroll
    for (int rf = 0; rf < NRF; ++rf)
#pragma unroll
      for (int r = 0; r < 4; ++r) {
        float inv = 1.0f / rsh[wr * MW + rf * 16 + l4 * 4 + r];
        int grow = m0 + wr * MW + rf * 16 + l4 * 4 + r;
#pragma unroll
        for (int cf = 0; cf < NCF2; ++cf)
          Cb[(size_t)grow * ldc + n0 + wc * NW + cf * 16 + l15] = acc[rf][cf][r] * inv;
      }
  } else {  // EPI == 4: fused K/V projection epilogue
    if (n0 < 1024) {
      bf16_t* Cb = (bf16_t*)Cv;  // K output, ldc = 1024, rows = 8192 (batch-folded)
#pragma unroll
      for (int rf = 0; rf < NRF; ++rf)
#pragma unroll
        for (int cf = 0; cf < NCF2; ++cf) {
          int grow = m0 + wr * MW + rf * 16 + l4 * 4;
          int gc = n0 + wc * NW + cf * 16 + l15;
#pragma unroll
          for (int r = 0; r < 4; ++r)
            Cb[(size_t)(grow + r) * ldc + gc] = (bf16_t)acc[rf][cf][r];
        }
    } else {
      bf16_t* VTb = (bf16_t*)Cv2;  // VT[b][d][kl]
#pragma unroll
      for (int rf = 0; rf < NRF; ++rf)
#pragma unroll
        for (int cf = 0; cf < NCF2; ++cf) {
          int grow0 = m0 + wr * MW + rf * 16 + l4 * 4;
          int b = grow0 >> 11, kl = grow0 & 2047;
          int d = (n0 - 1024) + wc * NW + cf * 16 + l15;
          bf16x4 v;
#pragma unroll
          for (int r = 0; r < 4; ++r) v[r] = (bf16_t)acc[rf][cf][r];
          *(bf16x4*)(VTb + (size_t)b * (1024 * 2048) + (size_t)d * 2048 + kl) = v;
        }
    }
  }
}

// ---------------- launcher ----------------
extern "C" void kernel_launch(void* const* d_in, const int* in_sizes, int n_in,
                              void* d_out, int out_size, void* d_ws, size_t ws_size,
                              hipStream_t stream) {
  const float* hs  = (const float*)d_in[0];   // [4,2048,1024]
  const float* dhs = (const float*)d_in[1];   // [4,2048,1024]
  const float* Wq  = (const float*)d_in[2];   // [1024,1024]
  const float* Wkv = (const float*)d_in[3];   // [1024,2048]
  float* out = (float*)d_out;

  const size_t M1 = 1024 * 1024;
  bf16_t* WqT  = (bf16_t*)d_ws;          // 1M elems  (Wq^T * 1/32)
  bf16_t* WkvT = WqT + M1;               // 2M elems  (rows 0..1023 = Wk^T, 1024..2047 = Wv^T)
  bf16_t* AB   = WkvT + 2 * M1;          // 16M elems shared region:
  bf16_t* dhsb = AB;                     //   dhs bf16 (dead after KV gemm)
  bf16_t* hsb  = AB + 8 * M1;            //   hs bf16  (dead after Q gemm)
  bf16_t* P    = AB;                     //   then: P [4][2048][2048]
  bf16_t* Kb   = AB + 16 * M1;           // 8M elems  K [4*2048][1024]
  bf16_t* VTb  = Kb + 8 * M1;            // 8M elems  VT [4][1024][2048]
  bf16_t* Qb   = VTb + 8 * M1;           // 8M elems  Q [4*2048][1024] (pre-scaled 1/32)
  float* rowsum = (float*)(Qb + 8 * M1); // 8192 fp32

  prep_kernel<<<2048 + 3072, 256, 0, stream>>>(dhs, hs, dhsb, hsb, rowsum,
                                               Wq, Wkv, WqT, WkvT);

  // KV = dhs @ Wkv : M=8192, N=2048, K=1024; K-half -> Kb, V-half -> VT
  gemm8<256, 4><<<256, 512, 0, stream>>>(
      dhsb, 1024, 0, WkvT, 1024, 0, Kb, 1024, 0, VTb, 8, 256, 1024, nullptr);
  // Q = hs @ (Wq/32) : M=8192, N=1024, K=1024
  gemm8<128, 0><<<256, 512, 0, stream>>>(
      hsb, 1024, 0, WqT, 1024, 0, Qb, 1024, 0, nullptr, 8, 256, 1024, nullptr);
  // P = exp(Q K^T - 16) + rowsums : per batch M=N=2048, K=1024
  gemm8<256, 1><<<256, 512, 0, stream>>>(
      Qb, 1024, (size_t)2048 * 1024, Kb, 1024, (size_t)2048 * 1024,
      P, 2048, (size_t)2048 * 2048, nullptr, 8, 64, 1024, rowsum);
  // out = (P @ V) / rowsum : per batch M=2048, N=1024, K=2048
  gemm8<128, 2><<<256, 512, 0, stream>>>(
      P, 2048, (size_t)2048 * 2048, VTb, 2048, (size_t)1024 * 2048,
      out, 1024, (size_t)2048 * 1024, nullptr, 8, 64, 2048, rowsum);
}